// Round 15
// baseline (65.914 us; speedup 1.0000x reference)
//
#include <hip/hip_runtime.h>
#include <hip/hip_bf16.h>

// Match numpy float32 semantics exactly: no FMA contraction, fixed op order.
#pragma clang fp contract(off)

#define B_ 8
#define N_ 4096
#define HALF 2048  // points staged per A-pass (2 passes)
#define C_ 128
#define CH 64      // c's per B-pass (2 passes over c-halves)
#define K_ 16      // SAMPLE (output neighbors)
#define S_ 20      // SAMPLE_NUM (ball_query nsample)
#define NW 8       // queries per block (1 per wave) -> 4096 blocks, phase mixing
#define R_ (NW * K_)   // 128 rows in transpose buffer
#define TP 65      // tbuf row pitch (odd -> stage writes ~2-way)
#define THREADS 512

typedef float f4 __attribute__((ext_vector_type(4)));
typedef float f2 __attribute__((ext_vector_type(2)));

// v_pk_*_f32: each 32-bit half is a full IEEE fp32 op -> bit-identical to the
// scalar sequence, 2 candidates per instruction.
__device__ __forceinline__ f2 pk_mul(f2 a, f2 b) {
    f2 d;
    asm("v_pk_mul_f32 %0, %1, %2" : "=v"(d) : "v"(a), "v"(b));
    return d;
}
__device__ __forceinline__ f2 pk_add(f2 a, f2 b) {
    f2 d;
    asm("v_pk_add_f32 %0, %1, %2" : "=v"(d) : "v"(a), "v"(b));
    return d;
}

// slot s in [0,20) -> output position k = s - 1 - s/5, valid iff s>0 && s%5!=0

__global__ __launch_bounds__(THREADS, 8) void fused_kernel(const float* __restrict__ xyz,
                                                           const float* __restrict__ feat,
                                                           float* __restrict__ out_xyz,
                                                           float* __restrict__ out_feat) {
#pragma clang fp contract(off)
    // ~33 KB union: phase A = SoA (X,Y,Z,SQ) half-batch (8192 floats);
    // phase B = transpose buffer [128 r][65 pitch] = 8320 floats
    __shared__ __align__(16) float smem[R_ * TP];
    __shared__ int sidx[NW * K_];
    float* const Xa = smem;
    float* const Ya = smem + HALF;
    float* const Za = smem + 2 * HALF;
    float* const Wa = smem + 3 * HALF;

    const int w    = blockIdx.x;        // 0..4095
    const int b    = w & 7;             // XCD-align: batch b lives on XCD b
    const int n0   = (w >> 3) * NW;
    const int t    = threadIdx.x;
    const int wave = t >> 6;            // 0..7
    const int lane = t & 63;
    const float* xb = xyz + (size_t)b * (N_ * 3);

    // ---------------- Phase A: 1 query per wave, two staged halves ----------
    {
        const int n  = n0 + wave;
        const float qx = xb[n * 3 + 0];
        const float qy = xb[n * 3 + 1];
        const float qz = xb[n * 3 + 2];
        const float sqn = (qx * qx + qy * qy) + qz * qz;   // exact ref op order

        const f2 qx2 = {qx, qx}, qy2 = {qy, qy}, qz2 = {qz, qz};
        const f2 sqn2 = {sqn, sqn};
        const f2 neg2 = {-2.0f, -2.0f};

        int run = 0;
        int first = -1;
        bool done = false;
        int* out = sidx + wave * K_;
        const unsigned long long below = (1ull << lane) - 1ull;

        for (int half = 0; half < 2; ++half) {
            __syncthreads();   // prior half's scan reads complete (no-op @ 0)
            // stage SoA; sq computed once, exact ref op order
            for (int p = t; p < HALF; p += THREADS) {
                const int gp = half * HALF + p;
                const float x = xb[gp * 3 + 0];
                const float y = xb[gp * 3 + 1];
                const float z = xb[gp * 3 + 2];
                Xa[p] = x; Ya[p] = y; Za[p] = z;
                Wa[p] = (x * x + y * y) + z * z;
            }
            __syncthreads();             // half staged

            if (done) continue;          // wave-uniform; still hits barriers

            for (int base = 0; base < HALF; base += 512) {
                const int gbase = half * HALF + base;
#pragma unroll
                for (int j = 0; j < 4; ++j) {
                    const int off = base + j * 128 + 2 * lane;
                    const f2 X2 = *reinterpret_cast<const f2*>(&Xa[off]);
                    const f2 Y2 = *reinterpret_cast<const f2*>(&Ya[off]);
                    const f2 Z2 = *reinterpret_cast<const f2*>(&Za[off]);
                    const f2 W2 = *reinterpret_cast<const f2*>(&Wa[off]);

                    // dt = (qx*x + qy*y) + qz*z ; d2 = (sqn+sq) + (-2)*dt
                    const f2 t0 = pk_mul(qx2, X2);
                    const f2 t1 = pk_mul(qy2, Y2);
                    const f2 t2 = pk_add(t0, t1);
                    const f2 t3 = pk_mul(qz2, Z2);
                    const f2 dt = pk_add(t2, t3);
                    const f2 sm = pk_add(sqn2, W2);
                    const f2 nv = pk_mul(neg2, dt);
                    const f2 d2 = pk_add(sm, nv);

                    const unsigned long long A0 = __ballot(d2.x < 256.0f);
                    const unsigned long long A1 = __ballot(d2.y < 256.0f);

                    if (A0 | A1) {        // wave-uniform skip of slot work
                        if (run == 0) {   // global first in-ball index
                            const int c0 = A0 ? 2 * (int)__builtin_ctzll(A0)
                                              : 0x7ffffff;
                            const int c1 = A1 ? 2 * (int)__builtin_ctzll(A1) + 1
                                              : 0x7ffffff;
                            first = gbase + j * 128 + (c0 < c1 ? c0 : c1);
                        }
                        // order within pair-block: index = 2*lane + h
                        const int p0 = (int)__popcll(A0 & below)
                                     + (int)__popcll(A1 & below);
                        const int s0 = run + p0;
                        const int s1 = s0 + (int)((A0 >> lane) & 1);
                        const int m  = gbase + j * 128 + 2 * lane;
                        if (((A0 >> lane) & 1) && s0 > 0 && s0 < S_ && (s0 % 5) != 0)
                            out[s0 - 1 - s0 / 5] = m;
                        if (((A1 >> lane) & 1) && s1 > 0 && s1 < S_ && (s1 % 5) != 0)
                            out[s1 - 1 - s1 / 5] = m + 1;
                    }
                    run += (int)__popcll(A0) + (int)__popcll(A1);
                }
                if (run >= S_) { done = true; break; }   // wave-uniform
            }
        }

        // pad slots [run, 20) with 'first'
        if (lane < S_ && lane >= run && lane > 0 && (lane % 5) != 0) {
            out[lane - 1 - lane / 5] = first;
        }
    }
    __syncthreads();   // sidx complete; all scan reads of smem done

    // ---------------- xyz gather (global scattered reads, L2-hot) -----------
    if (t < 3 * NW * K_) {                 // 384 threads
        const int j  = t >> 7;             // 0..2
        const int r  = t & 127;
        const int nl = r >> 4;             // 0..7
        const int k  = r & 15;
        __builtin_nontemporal_store(
            xb[(size_t)sidx[nl * K_ + k] * 3 + j],
            &out_xyz[((size_t)(b * 3 + j) * N_ + (n0 + nl)) * K_ + k]);
    }

    // ---------------- feature gather: 2 c-half passes, reg-pipelined --------
    // (byte-identical to R14: 512-B contiguous nt bursts per (c, pass))
    const float* fb = feat + (size_t)b * N_ * C_;
    float* ob = out_feat + (size_t)b * C_ * N_ * K_ + (size_t)n0 * K_;

    f4 v0, v1, v2, v3;
    const int sr0 = t >> 4,            scl = (t & 15) * 4;
    const int sr1 = (t + 512) >> 4;
    const int sr2 = (t + 1024) >> 4;
    const int sr3 = (t + 1536) >> 4;

#define LOADREGS(H)                                                             \
    do {                                                                        \
        const int cg = (H) * CH + scl;                                          \
        v0 = *reinterpret_cast<const f4*>(fb + (size_t)sidx[sr0] * C_ + cg);    \
        v1 = *reinterpret_cast<const f4*>(fb + (size_t)sidx[sr1] * C_ + cg);    \
        v2 = *reinterpret_cast<const f4*>(fb + (size_t)sidx[sr2] * C_ + cg);    \
        v3 = *reinterpret_cast<const f4*>(fb + (size_t)sidx[sr3] * C_ + cg);    \
    } while (0)

    LOADREGS(0);   // prologue (reads sidx + global only; smem untouched)

    for (int h = 0; h < 2; ++h) {
        __syncthreads();   // previous drain (or phase A) done with smem
        // commit pass h from regs into tbuf[r][cl..cl+3]
        smem[sr0 * TP + scl + 0] = v0.x; smem[sr0 * TP + scl + 1] = v0.y;
        smem[sr0 * TP + scl + 2] = v0.z; smem[sr0 * TP + scl + 3] = v0.w;
        smem[sr1 * TP + scl + 0] = v1.x; smem[sr1 * TP + scl + 1] = v1.y;
        smem[sr1 * TP + scl + 2] = v1.z; smem[sr1 * TP + scl + 3] = v1.w;
        smem[sr2 * TP + scl + 0] = v2.x; smem[sr2 * TP + scl + 1] = v2.y;
        smem[sr2 * TP + scl + 2] = v2.z; smem[sr2 * TP + scl + 3] = v2.w;
        smem[sr3 * TP + scl + 0] = v3.x; smem[sr3 * TP + scl + 1] = v3.y;
        smem[sr3 * TP + scl + 2] = v3.z; smem[sr3 * TP + scl + 3] = v3.w;

        if (h == 0) LOADREGS(1);   // L2 latency hides under drain of pass 0

        __syncthreads();
        // drain: e -> cl = e>>5 (0..63), r4 = (e&31)*4; 32 consecutive lanes
        // cover 512 contiguous bytes of one c-stream; nt f4 stores.
        for (int e = t; e < CH * R_ / 4; e += THREADS) {   // 2048 f4
            const int cl = e >> 5;
            const int r4 = (e & 31) * 4;
            f4 v;
            v.x = smem[(r4 + 0) * TP + cl];
            v.y = smem[(r4 + 1) * TP + cl];
            v.z = smem[(r4 + 2) * TP + cl];
            v.w = smem[(r4 + 3) * TP + cl];
            __builtin_nontemporal_store(
                v, reinterpret_cast<f4*>(
                       ob + (size_t)(h * CH + cl) * (N_ * K_) + r4));
        }
    }
#undef LOADREGS
}

extern "C" void kernel_launch(void* const* d_in, const int* in_sizes, int n_in,
                              void* d_out, int out_size, void* d_ws, size_t ws_size,
                              hipStream_t stream) {
    const float* xyz  = (const float*)d_in[0];   // (8, 4096, 3)
    const float* feat = (const float*)d_in[1];   // (8, 4096, 128)

    float* out_xyz  = (float*)d_out;                       // (8,3,4096,16)
    float* out_feat = out_xyz + (size_t)B_ * 3 * N_ * K_;  // (8,128,4096,16)

    // one block per (b, 8 consecutive queries); fused, no workspace
    hipLaunchKernelGGL(fused_kernel, dim3(B_ * N_ / NW), dim3(THREADS), 0, stream,
                       xyz, feat, out_xyz, out_feat);
}